// Round 3
// baseline (296.386 us; speedup 1.0000x reference)
//
#include <hip/hip_runtime.h>
#include <hip/hip_bf16.h>
#include <stdint.h>

// ---------------------------------------------------------------------------
// Block: LN -> [q,k,v,p] = h @ w_in^T -> key-smear -> causal attn w/ learned
// ALiBi -> o * silu(p) -> @ w_out^T -> LN.   B=2 L=2048 D=1024 H=16 Dh=128.
// Internal compute in bf16 MFMA.
// ---------------------------------------------------------------------------

typedef __bf16 bf16;
typedef bf16  bf16x8 __attribute__((ext_vector_type(8)));
typedef float f32x4  __attribute__((ext_vector_type(4)));

#define SEQ   2048
#define NBATC 2

__device__ __forceinline__ void gld_lds16(const bf16* g, bf16* l) {
  __builtin_amdgcn_global_load_lds((const __attribute__((address_space(1))) void*)g,
                                   (__attribute__((address_space(3))) void*)l, 16, 0, 0);
}

// ---------------- f32 -> bf16 convert (8 elems/thread) ----------------------
__global__ __launch_bounds__(256) void cvt_kernel(const float* __restrict__ in,
                                                  bf16* __restrict__ out, int n8) {
  int t = blockIdx.x * 256 + threadIdx.x;
  if (t >= n8) return;
  const float4* p = (const float4*)in + (size_t)t * 2;
  float4 a = p[0], b = p[1];
  bf16x8 o;
  o[0] = (bf16)a.x; o[1] = (bf16)a.y; o[2] = (bf16)a.z; o[3] = (bf16)a.w;
  o[4] = (bf16)b.x; o[5] = (bf16)b.y; o[6] = (bf16)b.z; o[7] = (bf16)b.w;
  *((bf16x8*)out + t) = o;
}

// ---------------- LayerNorm over rows of 1024 f32 ---------------------------
template<bool BF16OUT>
__global__ __launch_bounds__(256) void ln_kernel(const float* __restrict__ x,
    const float* __restrict__ gamma, const float* __restrict__ beta,
    void* __restrict__ out) {
  const int row = blockIdx.x;
  const int tid = threadIdx.x;
  float4 v = *(const float4*)(x + (size_t)row * 1024 + tid * 4);
  float s  = v.x + v.y + v.z + v.w;
  float ss = v.x * v.x + v.y * v.y + v.z * v.z + v.w * v.w;
#pragma unroll
  for (int m = 1; m < 64; m <<= 1) { s += __shfl_xor(s, m, 64); ss += __shfl_xor(ss, m, 64); }
  __shared__ float red[8];
  if ((tid & 63) == 0) { red[tid >> 6] = s; red[(tid >> 6) + 4] = ss; }
  __syncthreads();
  s  = red[0] + red[1] + red[2] + red[3];
  ss = red[4] + red[5] + red[6] + red[7];
  const float mu  = s * (1.f / 1024.f);
  const float inv = rsqrtf(ss * (1.f / 1024.f) - mu * mu + 1e-5f);
  float4 g  = *(const float4*)(gamma + tid * 4);
  float4 bb = *(const float4*)(beta  + tid * 4);
  float y0 = (v.x - mu) * inv * g.x + bb.x;
  float y1 = (v.y - mu) * inv * g.y + bb.y;
  float y2 = (v.z - mu) * inv * g.z + bb.z;
  float y3 = (v.w - mu) * inv * g.w + bb.w;
  if (BF16OUT) {
    bf16* o = (bf16*)out + (size_t)row * 1024 + tid * 4;
    o[0] = (bf16)y0; o[1] = (bf16)y1; o[2] = (bf16)y2; o[3] = (bf16)y3;
  } else {
    float* o = (float*)out + (size_t)row * 1024 + tid * 4;
    o[0] = y0; o[1] = y1; o[2] = y2; o[3] = y3;
  }
}

// ---------------- key smear -> ksm, stored XOR-swizzled ---------------------
__global__ __launch_bounds__(256) void smear_kernel(const bf16* __restrict__ qkvp,
    const float* __restrict__ smf, bf16* __restrict__ ksm) {
  int t  = blockIdx.x * 256 + threadIdx.x;   // 2^20 vec8 groups
  int d8 = t & 15;
  int i  = (t >> 4) & 2047;
  int h  = (t >> 15) & 15;
  int b  = t >> 19;
  float sm = 1.f / (1.f + __expf(-smf[h]));
  const bf16* base = qkvp + (size_t)(b * SEQ + i) * 8192 + 2048 + h * 128 + d8 * 8;
  bf16x8 cur = *(const bf16x8*)base;
  bf16x8 prv = cur;
  if (i > 0) prv = *(const bf16x8*)(base - 8192);
  bf16x8 o;
#pragma unroll
  for (int e = 0; e < 8; e++) {
    float pv = (i > 0) ? (float)prv[e] : 0.f;
    o[e] = (bf16)((1.f - sm) * (float)cur[e] + sm * pv);
  }
  size_t idx = ((size_t)(b * 16 + h) * SEQ + i) * 128 + ((d8 * 8) ^ ((i & 7) << 3));
  *(bf16x8*)(ksm + idx) = o;
}

// ---------------- V transpose: vt[bh][kt][d][i0..63], XOR-swizzled ----------
__global__ __launch_bounds__(256) void vtrans_kernel(const bf16* __restrict__ qkvp,
                                                     bf16* __restrict__ vt) {
  __shared__ bf16 T[128][72];
  const int kt = blockIdx.x, bh = blockIdx.y;
  const int b = bh >> 4, h = bh & 15;
  const int t = threadIdx.x;
  {
    int i = t >> 2, d0 = (t & 3) * 32;
    const bf16* src = qkvp + (size_t)(b * SEQ + kt * 64 + i) * 8192 + 4096 + h * 128 + d0;
#pragma unroll
    for (int m = 0; m < 4; m++) {
      bf16x8 v8 = *(const bf16x8*)(src + m * 8);
#pragma unroll
      for (int e = 0; e < 8; e++) T[d0 + m * 8 + e][i] = v8[e];
    }
  }
  __syncthreads();
  {
    int d = t >> 1, i0 = (t & 1) * 32;
    bf16* dst = vt + (size_t)bh * (SEQ * 128) + (size_t)kt * 8192 + d * 64;
#pragma unroll
    for (int m = 0; m < 4; m++) {
      bf16x8 v8 = *(const bf16x8*)&T[d][i0 + m * 8];
      *(bf16x8*)(dst + (((i0 + m * 8)) ^ ((d & 7) << 3))) = v8;
    }
  }
}

// ---------------- GEMM: C[M][N] = A[M][K] * Bt[N][K]^T  (bf16 MFMA) ---------
// 1D grid; supertile-chunked XCD swizzle: XCD j (= wgid&7) owns a compact
// SXxSY region of the (N/128)x(M/128) tile grid -> A/B panels stay in its L2.
template<typename OutT>
__global__ __launch_bounds__(256) void gemm_bt(const bf16* __restrict__ A,
    const bf16* __restrict__ Bt, OutT* __restrict__ C, int M, int N, int K,
    int RX, int SX, int SY) {
  __shared__ bf16 As[128 * 32];
  __shared__ bf16 Bs[128 * 32];
  const int w   = blockIdx.x;
  const int xcd = w & 7, idx = w >> 3;
  const int rx = xcd % RX, ry = xcd / RX;
  const int bx = rx * SX + idx % SX;
  const int by = ry * SY + idx / SX;
  const int tid  = threadIdx.x;
  const int lane = tid & 63, wid = tid >> 6;
  const int l4 = lane >> 4, l16 = lane & 15;
  const int wr = wid >> 1, wc = wid & 1;
  const int rowBase = by * 128, colBase = bx * 128;

  const bf16* gA = A  + (size_t)(rowBase + (tid >> 2)) * K + (tid & 3) * 8;
  const bf16* gB = Bt + (size_t)(colBase + (tid >> 2)) * K + (tid & 3) * 8;
  const size_t rowStep = (size_t)64 * K;

  f32x4 acc[4][4];
  const f32x4 z = {0.f, 0.f, 0.f, 0.f};
#pragma unroll
  for (int i = 0; i < 4; i++)
#pragma unroll
    for (int j = 0; j < 4; j++) acc[i][j] = z;

  for (int k0 = 0; k0 < K; k0 += 32) {
    __syncthreads();
    gld_lds16(gA + k0,           &As[tid * 8]);
    gld_lds16(gA + rowStep + k0, &As[2048 + tid * 8]);
    gld_lds16(gB + k0,           &Bs[tid * 8]);
    gld_lds16(gB + rowStep + k0, &Bs[2048 + tid * 8]);
    __syncthreads();
    bf16x8 af[4], bfr[4];
#pragma unroll
    for (int mi = 0; mi < 4; mi++)
      af[mi] = *(const bf16x8*)&As[(wr * 64 + mi * 16 + l16) * 32 + l4 * 8];
#pragma unroll
    for (int ni = 0; ni < 4; ni++)
      bfr[ni] = *(const bf16x8*)&Bs[(wc * 64 + ni * 16 + l16) * 32 + l4 * 8];
#pragma unroll
    for (int mi = 0; mi < 4; mi++)
#pragma unroll
      for (int ni = 0; ni < 4; ni++)
        acc[mi][ni] = __builtin_amdgcn_mfma_f32_16x16x32_bf16(af[mi], bfr[ni], acc[mi][ni], 0, 0, 0);
  }
#pragma unroll
  for (int mi = 0; mi < 4; mi++)
#pragma unroll
    for (int ni = 0; ni < 4; ni++) {
      int row = rowBase + wr * 64 + mi * 16 + l4 * 4;
      int col = colBase + wc * 64 + ni * 16 + l16;
#pragma unroll
      for (int r = 0; r < 4; r++)
        C[(size_t)(row + r) * N + col] = (OutT)acc[mi][ni][r];
    }
}

// ---------------- flash attention + ALiBi + causal + silu-gate --------------
// 1D grid 512, XCD-swizzled so each XCD owns 4 bh values (K/V strips L2-fit).
// Block handles q-tile pair (qp, 31-qp): uniform 33 K-tiles per block.
// exp2-domain online softmax, deferred l-reduction, defer-max rescale skip.
__global__ __launch_bounds__(256) void attn_kernel(const bf16* __restrict__ qkvp,
    const bf16* __restrict__ ksm, const bf16* __restrict__ vt,
    const float* __restrict__ slopes, bf16* __restrict__ gated) {
  const int w   = blockIdx.x;
  const int l   = (w & 7) * 64 + (w >> 3);   // XCD j -> bh in [4j, 4j+4)
  const int qp  = l & 15;
  const int bh  = l >> 4;
  const int b   = bh >> 4, h = bh & 15;
  const int tid = threadIdx.x, wid = tid >> 6, lane = tid & 63;
  const int l4 = lane >> 4, l16 = lane & 15;
  const float LOG2E = 1.44269504f;
  const float s2 = 0.08838834764831845f * LOG2E;   // (1/sqrt(128))*log2e
  const float slopeL = slopes[h] * LOG2E;

  __shared__ bf16 Kb[2][64 * 128];
  __shared__ bf16 Vb[2][64 * 128];
  __shared__ bf16 P_lds[64][72];

  const bf16* ksmB = ksm + (size_t)bh * SEQ * 128;
  const bf16* vtB  = vt  + (size_t)bh * SEQ * 128;

  auto stage = [&](int kt, int bsel) {
    const bf16* ks = ksmB + kt * 8192 + tid * 8;
    const bf16* vs = vtB  + kt * 8192 + tid * 8;
    bf16* kd = &Kb[bsel][tid * 8];
    bf16* vd = &Vb[bsel][tid * 8];
#pragma unroll
    for (int g = 0; g < 4; g++) {
      gld_lds16(ks + g * 2048, kd + g * 2048);
      gld_lds16(vs + g * 2048, vd + g * 2048);
    }
  };

  auto run_strip = [&](int qtile, int ntiles) {
    bf16x8 qf[4];
    {
      const bf16* qrow = qkvp + (size_t)(b * SEQ + qtile * 64 + wid * 16 + l16) * 8192 + h * 128;
#pragma unroll
      for (int kb = 0; kb < 4; kb++) qf[kb] = *(const bf16x8*)(qrow + kb * 32 + l4 * 8);
    }
    f32x4 oacc[8];
    const f32x4 z = {0.f, 0.f, 0.f, 0.f};
#pragma unroll
    for (int i = 0; i < 8; i++) oacc[i] = z;
    float m2[4], lpart[4];
#pragma unroll
    for (int r = 0; r < 4; r++) { m2[r] = -1e38f; lpart[r] = 0.f; }

    stage(0, 0);
    for (int t = 0; t < ntiles; ++t) {
      __syncthreads();                     // drains tile-t loads (vmcnt)
      if (t + 1 < ntiles) stage(t + 1, (t + 1) & 1);   // prefetch overlaps compute
      const bf16* K_ = Kb[t & 1];
      const bf16* V_ = Vb[t & 1];
      const int kt = t;

      // S = Q K^T  (per wave: 16 x 64), swizzled reads
      f32x4 sacc[4];
      __builtin_amdgcn_s_setprio(1);
#pragma unroll
      for (int jf = 0; jf < 4; jf++) {
        f32x4 a = z;
        const int row = jf * 16 + l16;
#pragma unroll
        for (int kb = 0; kb < 4; kb++) {
          bf16x8 kf = *(const bf16x8*)&K_[row * 128 + ((kb * 32 + l4 * 8) ^ ((row & 7) << 3))];
          a = __builtin_amdgcn_mfma_f32_16x16x32_bf16(qf[kb], kf, a, 0, 0, 0);
        }
        sacc[jf] = a;
      }
      __builtin_amdgcn_s_setprio(0);

      // exp2-domain: s*scale*log2e + j*slope*log2e, causal mask on diag tile
      const bool diag = (kt == qtile);
      float sadj[4][4];
#pragma unroll
      for (int jf = 0; jf < 4; jf++) {
        int j = kt * 64 + jf * 16 + l16;
        float bias2 = (float)j * slopeL;
#pragma unroll
        for (int r = 0; r < 4; r++) {
          float v = fmaf(sacc[jf][r], s2, bias2);
          if (diag) {
            int i = qtile * 64 + wid * 16 + l4 * 4 + r;
            if (j > i) v = -1e38f;
          }
          sadj[jf][r] = v;
        }
      }

      // online softmax: max-reduce per row; rescale only when max grows >14
      float p[4][4];
#pragma unroll
      for (int r = 0; r < 4; r++) {
        float mx = fmaxf(fmaxf(sadj[0][r], sadj[1][r]), fmaxf(sadj[2][r], sadj[3][r]));
#pragma unroll
        for (int m = 1; m < 16; m <<= 1) mx = fmaxf(mx, __shfl_xor(mx, m, 64));
        if (mx > m2[r] + 14.f) {           // defer-max: P bounded by 2^14
          float alpha = exp2f(m2[r] - mx);
          m2[r] = mx;
          lpart[r] *= alpha;
#pragma unroll
          for (int df = 0; df < 8; df++) oacc[df][r] *= alpha;
        }
        float rs = 0.f;
#pragma unroll
        for (int jf = 0; jf < 4; jf++) {
          float pe = exp2f(sadj[jf][r] - m2[r]);
          p[jf][r] = pe;
          rs += pe;
        }
        lpart[r] += rs;                    // per-lane partial; reduced at end
      }

      // P -> LDS (per-wave private rows), then PV via MFMA (swizzled V reads)
#pragma unroll
      for (int jf = 0; jf < 4; jf++)
#pragma unroll
        for (int r = 0; r < 4; r++)
          P_lds[wid * 16 + l4 * 4 + r][jf * 16 + l16] = (bf16)p[jf][r];

      __builtin_amdgcn_s_setprio(1);
#pragma unroll
      for (int kb2 = 0; kb2 < 2; ++kb2) {
        bf16x8 pf = *(const bf16x8*)&P_lds[wid * 16 + l16][kb2 * 32 + l4 * 8];
#pragma unroll
        for (int df = 0; df < 8; df++) {
          const int d = df * 16 + l16;
          bf16x8 vf = *(const bf16x8*)&V_[d * 64 + ((kb2 * 32 + l4 * 8) ^ ((d & 7) << 3))];
          oacc[df] = __builtin_amdgcn_mfma_f32_16x16x32_bf16(pf, vf, oacc[df], 0, 0, 0);
        }
      }
      __builtin_amdgcn_s_setprio(0);
    }

    // epilogue: reduce l partials, normalize, gate with silu(p), store bf16
    float linv[4];
#pragma unroll
    for (int r = 0; r < 4; r++) {
      float lr = lpart[r];
#pragma unroll
      for (int m = 1; m < 16; m <<= 1) lr += __shfl_xor(lr, m, 64);
      linv[r] = 1.f / lr;
    }
#pragma unroll
    for (int df = 0; df < 8; df++) {
      int d = df * 16 + l16;
#pragma unroll
      for (int r = 0; r < 4; r++) {
        int i = qtile * 64 + wid * 16 + l4 * 4 + r;
        float o = oacc[df][r] * linv[r];
        float pg = (float)qkvp[(size_t)(b * SEQ + i) * 8192 + 6144 + h * 128 + d];
        float silu = pg / (1.f + __expf(-pg));
        gated[(size_t)(b * SEQ + i) * 2048 + h * 128 + d] = (bf16)(silu * o);
      }
    }
  };

  run_strip(qp, qp + 1);
  __syncthreads();        // protect Kb[0]/Vb[0] before strip B's prologue stage
  run_strip(31 - qp, 32 - qp);
}

// ---------------------------------------------------------------------------
extern "C" void kernel_launch(void* const* d_in, const int* in_sizes, int n_in,
                              void* d_out, int out_size, void* d_ws, size_t ws_size,
                              hipStream_t stream) {
  (void)in_sizes; (void)n_in; (void)out_size; (void)ws_size;
  const float* x      = (const float*)d_in[0];
  const float* w_in   = (const float*)d_in[1];
  const float* w_out  = (const float*)d_in[2];
  const float* lnig   = (const float*)d_in[3];
  const float* lnib   = (const float*)d_in[4];
  const float* lnog   = (const float*)d_in[5];
  const float* lnob   = (const float*)d_in[6];
  const float* slopes = (const float*)d_in[7];
  const float* smf    = (const float*)d_in[8];
  float* out = (float*)d_out;

  char* ws = (char*)d_ws;
  size_t off = 0;
  bf16* hb      = (bf16*)(ws + off); off += (size_t)4096 * 1024 * 2;  // h (bf16)
  bf16* w_in_b  = (bf16*)(ws + off); off += (size_t)8192 * 1024 * 2;
  bf16* w_out_b = (bf16*)(ws + off); off += (size_t)1024 * 2048 * 2;
  bf16* qkvp    = (bf16*)(ws + off); off += (size_t)4096 * 8192 * 2;
  bf16* ksm     = (bf16*)(ws + off); off += (size_t)32 * 2048 * 128 * 2;
  bf16* gated   = (bf16*)(ws + off); off += (size_t)4096 * 2048 * 2;
  float* yb     = (float*)(ws + off); off += (size_t)4096 * 1024 * 4;
  bf16* vt      = (bf16*)yb;  // alias: vt dead before gemm2 writes yb

  cvt_kernel<<<4096, 256, 0, stream>>>(w_in,  w_in_b,  8388608 / 8);
  cvt_kernel<<<1024, 256, 0, stream>>>(w_out, w_out_b, 2097152 / 8);
  ln_kernel<true><<<4096, 256, 0, stream>>>(x, lnig, lnib, hb);
  gemm_bt<bf16><<<2048, 256, 0, stream>>>(hb, w_in_b, qkvp, 4096, 8192, 1024, 4, 16, 16);
  smear_kernel<<<4096, 256, 0, stream>>>(qkvp, smf, ksm);
  vtrans_kernel<<<dim3(32, 32), 256, 0, stream>>>(qkvp, vt);
  attn_kernel<<<512, 256, 0, stream>>>(qkvp, ksm, vt, slopes, gated);
  gemm_bt<float><<<256, 256, 0, stream>>>(gated, w_out_b, yb, 4096, 1024, 2048, 1, 8, 4);
  ln_kernel<false><<<4096, 256, 0, stream>>>(yb, lnog, lnob, out);
}